// Round 2
// baseline (350.640 us; speedup 1.0000x reference)
//
#include <hip/hip_runtime.h>
#include <hip/hip_bf16.h>
#include <stdint.h>

typedef __bf16 bf16x8 __attribute__((ext_vector_type(8)));
typedef float  f32x4  __attribute__((ext_vector_type(4)));

#define VOCAB 4096
#define DIM   256
#define NROWS 65536          // 32*2048
#define THREADS 128          // 2 waves
#define RPB   128            // rows per block (64 per wave, 4 rowsets of 16)
#define CTILE 64             // codebook cols per tile
#define NTILES (VOCAB / CTILE)
#define PAIRS 32             // 4 sub * 8 ch fragments per tile

#define GLOBAL_AS __attribute__((address_space(1)))
#define LDS_AS    __attribute__((address_space(3)))

static __device__ __forceinline__ uint16_t f2bf(float f) {
    __bf16 h = (__bf16)f;
    union { __bf16 h; uint16_t u; } c; c.h = h; return c.u;
}

// Prep: ebf = bf16(-2*emb), e2[v] = sum(emb[v]^2) fp32, zero the loss slot.
__global__ void vq_prep(const float* __restrict__ emb, uint16_t* __restrict__ ebf,
                        float* __restrict__ e2, float* __restrict__ loss_slot) {
    int wave = threadIdx.x >> 6, lane = threadIdx.x & 63;
    int row = blockIdx.x * 4 + wave;                      // 1024 blocks * 4 rows
    const float4* src = (const float4*)(emb + (size_t)row * DIM);
    float4 v = src[lane];
    float ss = v.x*v.x + v.y*v.y + v.z*v.z + v.w*v.w;
    ushort4 o;
    o.x = f2bf(-2.f*v.x); o.y = f2bf(-2.f*v.y);
    o.z = f2bf(-2.f*v.z); o.w = f2bf(-2.f*v.w);
    ((ushort4*)(ebf + (size_t)row * DIM))[lane] = o;
    #pragma unroll
    for (int off = 32; off; off >>= 1) ss += __shfl_down(ss, off);
    if (lane == 0) e2[row] = ss;
    if (blockIdx.x == 0 && threadIdx.x == 0) loss_slot[0] = 0.f;
}

__global__ __launch_bounds__(THREADS, 1) void vq_main(
        const float* __restrict__ x, const uint16_t* __restrict__ ebf,
        const float* __restrict__ e2, const float* __restrict__ emb,
        float* __restrict__ out, float* __restrict__ loss_slot) {
    // B tiles in MFMA-fragment order: [pair = sub*8+ch][lane] x 16B.
    // global_load_lds writes lane*16B at a uniform base -> layout matches exactly;
    // ds_read_b128 at lane*16B is the linear conflict-free pattern.
    __shared__ __align__(16) uint16_t Bb[2][PAIRS * 512];   // 2 x 32 KiB
    __shared__ int   idx_lds[RPB];
    __shared__ float wsum[2];

    const int tid  = threadIdx.x;
    const int wave = tid >> 6;
    const int lane = tid & 63;
    const int quad = lane >> 4;
    const int l16  = lane & 15;
    const int rowblock = blockIdx.x * RPB;
    const int waverow  = rowblock + wave * 64;

    // ---- A fragments: 64 rows/wave, register-resident for the whole loop ----
    // A layout: A[m = lane&15][k = quad*8 + j]
    bf16x8 A[4][8];
    #pragma unroll
    for (int rs = 0; rs < 4; ++rs) {
        const float* xrow = x + (size_t)(waverow + rs*16 + l16) * DIM;
        #pragma unroll
        for (int ch = 0; ch < 8; ++ch) {
            const float4* p = (const float4*)(xrow + ch*32 + quad*8);
            float4 a = p[0], b = p[1];
            bf16x8 f;
            f[0]=(__bf16)a.x; f[1]=(__bf16)a.y; f[2]=(__bf16)a.z; f[3]=(__bf16)a.w;
            f[4]=(__bf16)b.x; f[5]=(__bf16)b.y; f[6]=(__bf16)b.z; f[7]=(__bf16)b.w;
            A[rs][ch] = f;
        }
    }

    float minv[4][4];
    int   mini[4][4];
    #pragma unroll
    for (int rs = 0; rs < 4; ++rs)
        #pragma unroll
        for (int r = 0; r < 4; ++r) { minv[rs][r] = 3.402823466e+38f; mini[rs][r] = 0; }

    // ---- Async stage of one 64-col tile into Bb[buf] (16 DMA instrs per wave) ----
    auto stage = [&](int ct, int buf) {
        const uint16_t* srcbase = ebf + (size_t)(ct * CTILE + l16) * DIM + quad * 8;
        #pragma unroll
        for (int i = 0; i < 16; ++i) {
            const int p = wave * 16 + i;                 // fragment pair this wave stages
            const uint16_t* src = srcbase + (p >> 3) * (16 * DIM) + (p & 7) * 32;
            uint16_t* dst = &Bb[buf][p * 512];           // wave-uniform base
            __builtin_amdgcn_global_load_lds((const GLOBAL_AS void*)src,
                                             (LDS_AS void*)dst, 16, 0, 0);
        }
    };

    stage(0, 0);
    for (int ct = 0; ct < NTILES; ++ct) {
        const int cur = ct & 1;
        // Barrier drains vmcnt(0): Bb[cur] (issued a full tile ago) is ready, and
        // every wave has finished reading Bb[cur^1] -> safe to refill it.
        __syncthreads();
        if (ct + 1 < NTILES) stage(ct + 1, cur ^ 1);

        const int colbase = ct * CTILE;
        float ez[4];
        #pragma unroll
        for (int sub = 0; sub < 4; ++sub) ez[sub] = e2[colbase + sub*16 + l16];

        #pragma unroll
        for (int sub = 0; sub < 4; ++sub) {
            f32x4 acc[4];
            #pragma unroll
            for (int rs = 0; rs < 4; ++rs) acc[rs] = (f32x4){ez[sub], ez[sub], ez[sub], ez[sub]};
            #pragma unroll
            for (int ch = 0; ch < 8; ++ch) {
                bf16x8 b = *(const bf16x8*)&Bb[cur][((sub*8 + ch)*64 + lane) * 8];
                #pragma unroll
                for (int rs = 0; rs < 4; ++rs)
                    acc[rs] = __builtin_amdgcn_mfma_f32_16x16x32_bf16(A[rs][ch], b, acc[rs], 0, 0, 0);
            }
            const int colv = colbase + sub*16 + l16;
            // C layout: row = quad*4 + r (within rowset), col = l16.
            #pragma unroll
            for (int rs = 0; rs < 4; ++rs)
                #pragma unroll
                for (int r = 0; r < 4; ++r)
                    if (acc[rs][r] < minv[rs][r]) { minv[rs][r] = acc[rs][r]; mini[rs][r] = colv; }
        }
    }

    // ---- Reduce across the 16 lanes of each quad (same rows, different cols) ----
    #pragma unroll
    for (int rs = 0; rs < 4; ++rs) {
        #pragma unroll
        for (int r = 0; r < 4; ++r) {
            float v = minv[rs][r]; int ix = mini[rs][r];
            #pragma unroll
            for (int off = 8; off; off >>= 1) {
                float ov = __shfl_xor(v, off);
                int   oi = __shfl_xor(ix, off);
                if (ov < v || (ov == v && oi < ix)) { v = ov; ix = oi; }
            }
            if (l16 == 0) idx_lds[wave*64 + rs*16 + quad*4 + r] = ix;
        }
    }
    __syncthreads();

    // ---- Epilogue: gather emb[idx] (fp32 exact), write out, accumulate loss ----
    float lsum = 0.f;
    #pragma unroll 4
    for (int it = 0; it < 64; ++it) {
        int fi  = it * THREADS + tid;      // float4 index within block tile
        int row = fi >> 6;                 // 64 float4 per row
        int c4  = fi & 63;
        int e   = idx_lds[row];
        float4 q  = ((const float4*)(emb + (size_t)e * DIM))[c4];
        float4 xv = ((const float4*)(x + (size_t)(rowblock + row) * DIM))[c4];
        ((float4*)(out + (size_t)(rowblock + row) * DIM))[c4] = q;
        float dx = q.x - xv.x, dy = q.y - xv.y, dz = q.z - xv.z, dw = q.w - xv.w;
        lsum += dx*dx + dy*dy + dz*dz + dw*dw;
    }
    #pragma unroll
    for (int off = 32; off; off >>= 1) lsum += __shfl_down(lsum, off);
    if (lane == 0) wsum[wave] = lsum;
    __syncthreads();
    if (tid == 0) {
        float s = wsum[0] + wsum[1];
        atomicAdd(loss_slot, s * (1.25f / 16777216.f));
    }
}

extern "C" void kernel_launch(void* const* d_in, const int* in_sizes, int n_in,
                              void* d_out, int out_size, void* d_ws, size_t ws_size,
                              hipStream_t stream) {
    const float* x   = (const float*)d_in[0];   // [32,2048,256]
    const float* emb = (const float*)d_in[1];   // [4096,256]
    float* out = (float*)d_out;                 // 16777216 quantised_st + 1 loss
    uint16_t* ebf = (uint16_t*)d_ws;                          // 2 MB bf16(-2*emb)
    float* e2 = (float*)((char*)d_ws + (size_t)VOCAB*DIM*2);  // 16 KB
    float* loss_slot = out + (size_t)NROWS * DIM;

    vq_prep<<<VOCAB/4, 256, 0, stream>>>(emb, ebf, e2, loss_slot);
    vq_main<<<NROWS/RPB, THREADS, 0, stream>>>(x, ebf, e2, emb, out, loss_slot);
}

// Round 3
// 275.615 us; speedup vs baseline: 1.2722x; 1.2722x over previous
//
#include <hip/hip_runtime.h>
#include <hip/hip_bf16.h>
#include <stdint.h>

typedef __bf16 bf16x8 __attribute__((ext_vector_type(8)));
typedef float  f32x4  __attribute__((ext_vector_type(4)));

#define VOCAB 4096
#define DIM   256
#define NROWS 65536          // 32*2048
#define HALFC 2048           // cols per block (codebook split across 2 blocks)
#define CTILE 32             // cols per LDS tile
#define NT    (HALFC/CTILE)  // 64 tiles
#define RPB   128            // rows per block (2 waves x 64 rows)

#define GLOBAL_AS __attribute__((address_space(1)))
#define LDS_AS    __attribute__((address_space(3)))

static __device__ __forceinline__ uint16_t f2bf(float f) {
    __bf16 h = (__bf16)f;
    union { __bf16 h; uint16_t u; } c; c.h = h; return c.u;
}

// Prep: ebf = bf16(-2*emb), e2[v] = sum(emb[v]^2) fp32, zero the loss slot.
__global__ void vq_prep(const float* __restrict__ emb, uint16_t* __restrict__ ebf,
                        float* __restrict__ e2, float* __restrict__ loss_slot) {
    int wave = threadIdx.x >> 6, lane = threadIdx.x & 63;
    int row = blockIdx.x * 4 + wave;                      // 1024 blocks * 4 rows
    const float4* src = (const float4*)(emb + (size_t)row * DIM);
    float4 v = src[lane];
    float ss = v.x*v.x + v.y*v.y + v.z*v.z + v.w*v.w;
    ushort4 o;
    o.x = f2bf(-2.f*v.x); o.y = f2bf(-2.f*v.y);
    o.z = f2bf(-2.f*v.z); o.w = f2bf(-2.f*v.w);
    ((ushort4*)(ebf + (size_t)row * DIM))[lane] = o;
    #pragma unroll
    for (int off = 32; off; off >>= 1) ss += __shfl_down(ss, off);
    if (lane == 0) e2[row] = ss;
    if (blockIdx.x == 0 && threadIdx.x == 0) loss_slot[0] = 0.f;
}

// K1: per (128-row group, col-half) block -> per-row packed (score,idx) candidate.
__global__ __launch_bounds__(128, 2) void vq_argmin(
        const float* __restrict__ x, const uint16_t* __restrict__ ebf,
        const float* __restrict__ e2, unsigned long long* __restrict__ cand) {
    // B tiles in MFMA-fragment order: [pair = sub*8+ch][lane] x 16B.
    __shared__ __align__(16) uint16_t Bb[2][16 * 512];   // 2 x 16 KiB

    const int tid  = threadIdx.x;
    const int wave = tid >> 6;
    const int lane = tid & 63;
    const int quad = lane >> 4;
    const int l16  = lane & 15;
    const int rowgroup = blockIdx.x >> 1;
    const int half     = blockIdx.x & 1;
    const int rowblock = rowgroup * RPB;
    const int waverow  = rowblock + wave * 64;
    const int colhalf  = half * HALFC;

    // ---- A fragments: 64 rows/wave, register-resident (128 VGPRs) ----
    // A layout: A[m = lane&15][k = quad*8 + j]
    bf16x8 A[4][8];
    #pragma unroll
    for (int rs = 0; rs < 4; ++rs) {
        const float* xrow = x + (size_t)(waverow + rs*16 + l16) * DIM;
        #pragma unroll
        for (int ch = 0; ch < 8; ++ch) {
            const float4* p = (const float4*)(xrow + ch*32 + quad*8);
            float4 a = p[0], b = p[1];
            bf16x8 f;
            f[0]=(__bf16)a.x; f[1]=(__bf16)a.y; f[2]=(__bf16)a.z; f[3]=(__bf16)a.w;
            f[4]=(__bf16)b.x; f[5]=(__bf16)b.y; f[6]=(__bf16)b.z; f[7]=(__bf16)b.w;
            A[rs][ch] = f;
        }
    }

    float minv[4][4];
    int   mini[4][4];
    #pragma unroll
    for (int rs = 0; rs < 4; ++rs)
        #pragma unroll
        for (int r = 0; r < 4; ++r) { minv[rs][r] = 3.402823466e+38f; mini[rs][r] = 0; }

    // ---- Async stage of one 32-col tile (16 KB): 8 DMA instrs per wave ----
    auto stage = [&](int ct, int buf) {
        const uint16_t* srcbase = ebf + (size_t)(colhalf + ct * CTILE + l16) * DIM + quad * 8;
        #pragma unroll
        for (int i = 0; i < 8; ++i) {
            const int p = wave * 8 + i;                  // pair = sub*8 + ch
            const uint16_t* src = srcbase + (p >> 3) * (16 * DIM) + (p & 7) * 32;
            uint16_t* dst = &Bb[buf][p * 512];           // wave-uniform base
            __builtin_amdgcn_global_load_lds((const GLOBAL_AS void*)src,
                                             (LDS_AS void*)dst, 16, 0, 0);
        }
    };

    // e2 pipelined one tile ahead (registers).
    float ezc[2];
    ezc[0] = e2[colhalf + l16];
    ezc[1] = e2[colhalf + 16 + l16];
    stage(0, 0);

    for (int ct = 0; ct < NT; ++ct) {
        const int cur = ct & 1;
        // Barrier drains vmcnt(0): Bb[cur] (staged last iter) ready; Bb[cur^1] free.
        __syncthreads();
        if (ct + 1 < NT) stage(ct + 1, cur ^ 1);
        const int nxt = (ct + 1 < NT) ? (ct + 1) : ct;
        float ezn0 = e2[colhalf + nxt*CTILE + l16];
        float ezn1 = e2[colhalf + nxt*CTILE + 16 + l16];

        const int colbase = colhalf + ct * CTILE;
        #pragma unroll
        for (int sub = 0; sub < 2; ++sub) {
            const float ez = sub ? ezc[1] : ezc[0];
            f32x4 acc[4];
            #pragma unroll
            for (int rs = 0; rs < 4; ++rs) acc[rs] = (f32x4){ez, ez, ez, ez};
            #pragma unroll
            for (int ch = 0; ch < 8; ++ch) {
                bf16x8 b = *(const bf16x8*)&Bb[cur][((sub*8 + ch)*64 + lane) * 8];
                #pragma unroll
                for (int rs = 0; rs < 4; ++rs)
                    acc[rs] = __builtin_amdgcn_mfma_f32_16x16x32_bf16(A[rs][ch], b, acc[rs], 0, 0, 0);
            }
            const int colv = colbase + sub*16 + l16;
            // C layout: row = quad*4 + r (within rowset), col = l16.
            #pragma unroll
            for (int rs = 0; rs < 4; ++rs)
                #pragma unroll
                for (int r = 0; r < 4; ++r)
                    if (acc[rs][r] < minv[rs][r]) { minv[rs][r] = acc[rs][r]; mini[rs][r] = colv; }
        }
        ezc[0] = ezn0; ezc[1] = ezn1;
    }

    // ---- Reduce across 16 lanes of each quad; emit packed (sortable score, idx) ----
    #pragma unroll
    for (int rs = 0; rs < 4; ++rs) {
        #pragma unroll
        for (int r = 0; r < 4; ++r) {
            float v = minv[rs][r]; int ix = mini[rs][r];
            #pragma unroll
            for (int off = 8; off; off >>= 1) {
                float ov = __shfl_xor(v, off);
                int   oi = __shfl_xor(ix, off);
                if (ov < v || (ov == v && oi < ix)) { v = ov; ix = oi; }
            }
            if (l16 == 0) {
                unsigned su = __float_as_uint(v);
                su = (su & 0x80000000u) ? ~su : (su | 0x80000000u);
                unsigned long long pk = ((unsigned long long)su << 32) | (unsigned)ix;
                cand[(size_t)half * NROWS + waverow + rs*16 + quad*4 + r] = pk;
            }
        }
    }
}

// K2: merge halves, gather emb[idx], write out, accumulate loss. HBM-bound.
__global__ __launch_bounds__(256) void vq_out(
        const float* __restrict__ x, const float* __restrict__ emb,
        const unsigned long long* __restrict__ cand,
        float* __restrict__ out, float* __restrict__ loss_slot) {
    __shared__ int idx_lds[64];
    __shared__ float wsum[4];
    const int tid = threadIdx.x;
    const int rowblock = blockIdx.x * 64;
    if (tid < 64) {
        unsigned long long p0 = cand[rowblock + tid];
        unsigned long long p1 = cand[NROWS + rowblock + tid];
        unsigned long long w = p0 < p1 ? p0 : p1;   // tie -> lower idx (first-min)
        idx_lds[tid] = (int)(unsigned)(w & 0xffffffffull);
    }
    __syncthreads();

    float lsum = 0.f;
    #pragma unroll 4
    for (int it = 0; it < 16; ++it) {
        int fi  = it * 256 + tid;          // 4096 float4 per 64-row tile
        int row = fi >> 6;
        int c4  = fi & 63;
        int e   = idx_lds[row];
        float4 q  = ((const float4*)(emb + (size_t)e * DIM))[c4];
        float4 xv = ((const float4*)(x + (size_t)(rowblock + row) * DIM))[c4];
        ((float4*)(out + (size_t)(rowblock + row) * DIM))[c4] = q;
        float dx = q.x - xv.x, dy = q.y - xv.y, dz = q.z - xv.z, dw = q.w - xv.w;
        lsum += dx*dx + dy*dy + dz*dz + dw*dw;
    }
    #pragma unroll
    for (int off = 32; off; off >>= 1) lsum += __shfl_down(lsum, off);
    int lane = tid & 63, wave = tid >> 6;
    if (lane == 0) wsum[wave] = lsum;
    __syncthreads();
    if (tid == 0) {
        float s = wsum[0] + wsum[1] + wsum[2] + wsum[3];
        atomicAdd(loss_slot, s * (1.25f / 16777216.f));
    }
}

extern "C" void kernel_launch(void* const* d_in, const int* in_sizes, int n_in,
                              void* d_out, int out_size, void* d_ws, size_t ws_size,
                              hipStream_t stream) {
    const float* x   = (const float*)d_in[0];   // [32,2048,256]
    const float* emb = (const float*)d_in[1];   // [4096,256]
    float* out = (float*)d_out;                 // 16777216 quantised_st + 1 loss
    uint16_t* ebf = (uint16_t*)d_ws;                                  // 2 MB
    float* e2 = (float*)((char*)d_ws + (size_t)VOCAB*DIM*2);          // 16 KB
    unsigned long long* cand =
        (unsigned long long*)((char*)d_ws + (size_t)VOCAB*DIM*2 + VOCAB*4); // 1 MB
    float* loss_slot = out + (size_t)NROWS * DIM;

    vq_prep<<<VOCAB/4, 256, 0, stream>>>(emb, ebf, e2, loss_slot);
    vq_argmin<<<(NROWS/RPB)*2, 128, 0, stream>>>(x, ebf, e2, cand);
    vq_out<<<NROWS/64, 256, 0, stream>>>(x, emb, cand, out, loss_slot);
}

// Round 4
// 248.556 us; speedup vs baseline: 1.4107x; 1.1089x over previous
//
#include <hip/hip_runtime.h>
#include <stdint.h>

typedef float f32x4 __attribute__((ext_vector_type(4)));
typedef long  i64x2 __attribute__((ext_vector_type(2)));

#define VOCAB 4096
#define DIM   256
#define NROWS 65536            // 32*2048
#define SPLITS 4
#define COLS_PER (VOCAB/SPLITS) // 1024 cols per block
#define CTILE 32
#define NT (COLS_PER/CTILE)     // 32 tiles
#define RPB 128                 // rows per block (2 waves x 64)
#define SSCALE 4096.0f          // score scale: emb too small for e4m3 otherwise

#define GLOBAL_AS __attribute__((address_space(1)))
#define LDS_AS    __attribute__((address_space(3)))

// Pack 8 consecutive-k floats -> 8 fp8 bytes (one i64 MFMA operand).
// A and B both use THIS helper, so any byte-permutation of cvt_pk cancels
// in the dot product (A byte j always multiplies B byte j).
static __device__ __forceinline__ long pk8(float4 a, float4 b) {
    int lo = __builtin_amdgcn_cvt_pk_fp8_f32(a.x, a.y, 0, false);
    lo     = __builtin_amdgcn_cvt_pk_fp8_f32(a.z, a.w, lo, true);
    int hi = __builtin_amdgcn_cvt_pk_fp8_f32(b.x, b.y, 0, false);
    hi     = __builtin_amdgcn_cvt_pk_fp8_f32(b.z, b.w, hi, true);
    return (long)(unsigned)lo | ((long)hi << 32);
}

// Prep: eimg = fp8(-2*S*emb) pre-swizzled into per-tile fragment order, plus
// e2s[v] = S*sum(emb[v]^2). One block per 16-col group.
// Image layout: group g (16 cols): [cp 0..3][lane 0..63] x 16B, where
// lane = quad*16 + n (n = col within group), 16B = k-chunks {cp*64+quad*8 .. +7}
// (ch=2cp) and {cp*64+32+quad*8 .. +7} (ch=2cp+1).
__global__ void vq_prep(const float* __restrict__ emb, uint8_t* __restrict__ eimg,
                        float* __restrict__ e2s) {
    const int g = blockIdx.x, tid = threadIdx.x;
    const int cp = tid >> 6, lane = tid & 63;
    const int q = lane >> 4, n = lane & 15;
    const float* base = emb + (size_t)(g*16 + n)*DIM + cp*64 + q*8;
    float4 a0 = ((const float4*)base)[0];
    float4 a1 = ((const float4*)(base + 4))[0];
    float4 b0 = ((const float4*)(base + 32))[0];
    float4 b1 = ((const float4*)(base + 36))[0];
    const float s = -2.0f * SSCALE;
    float4 sa0 = {s*a0.x, s*a0.y, s*a0.z, s*a0.w};
    float4 sa1 = {s*a1.x, s*a1.y, s*a1.z, s*a1.w};
    float4 sb0 = {s*b0.x, s*b0.y, s*b0.z, s*b0.w};
    float4 sb1 = {s*b1.x, s*b1.y, s*b1.z, s*b1.w};
    i64x2 L; L.x = pk8(sa0, sa1); L.y = pk8(sb0, sb1);
    *(i64x2*)(eimg + (size_t)g*4096 + cp*1024 + lane*16) = L;

    // e2s: 16 threads per col, each sums a 16-elem segment, shuffle-reduce.
    const int c = tid >> 4, seg = tid & 15;
    const float4* er = (const float4*)(emb + (size_t)(g*16 + c)*DIM + seg*16);
    float ss = 0.f;
    #pragma unroll
    for (int i = 0; i < 4; ++i) {
        float4 v = er[i];
        ss += v.x*v.x + v.y*v.y + v.z*v.z + v.w*v.w;
    }
    ss += __shfl_xor(ss, 8); ss += __shfl_xor(ss, 4);
    ss += __shfl_xor(ss, 2); ss += __shfl_xor(ss, 1);
    if (seg == 0) e2s[g*16 + c] = SSCALE * ss;
}

// K1: fp8 MFMA argmin. 2048 blocks (512 rowgroups x 4 col-splits), 2 waves.
// Per-row winner stored as mantissa-packed float: (score & ~0xFFF) | col.
__global__ __launch_bounds__(128, 3) void vq_argmin(
        const float* __restrict__ x, const uint8_t* __restrict__ eimg,
        const float* __restrict__ e2s, float* __restrict__ cand) {
    __shared__ __align__(16) uint8_t Bb[2][8192];   // 2 x 8 KiB fp8 tiles

    const int tid  = threadIdx.x;
    const int wave = tid >> 6;
    const int lane = tid & 63;
    const int quad = lane >> 4;
    const int l16  = lane & 15;
    const int split    = blockIdx.x & (SPLITS - 1);
    const int rowgroup = blockIdx.x >> 2;
    const int rowblock = rowgroup * RPB;
    const int waverow  = rowblock + wave * 64;
    const int colhalf  = split * COLS_PER;

    // ---- A fragments: fp8(x), 64 rows/wave = 64 VGPRs, register-resident ----
    long A[4][8];
    #pragma unroll
    for (int rs = 0; rs < 4; ++rs) {
        const float* xrow = x + (size_t)(waverow + rs*16 + l16) * DIM;
        #pragma unroll
        for (int ch = 0; ch < 8; ++ch) {
            const float4* p = (const float4*)(xrow + ch*32 + quad*8);
            A[rs][ch] = pk8(p[0], p[1]);
        }
    }

    float rmin[4][4];
    #pragma unroll
    for (int rs = 0; rs < 4; ++rs)
        #pragma unroll
        for (int r = 0; r < 4; ++r) rmin[rs][r] = 3.402823466e+38f;

    // ---- Async stage one 32-col tile (8 KB): 4 DMA instrs per wave ----
    auto stage = [&](int ct, int buf) {
        const uint8_t* gbase = eimg + (size_t)(colhalf/16 + ct*2) * 4096;
        #pragma unroll
        for (int i = 0; i < 4; ++i) {
            const int p = wave * 4 + i;              // p = sub*4 + cp
            const uint8_t* src = gbase + p*1024 + lane*16;
            uint8_t* dst = &Bb[buf][p*1024];         // wave-uniform base
            __builtin_amdgcn_global_load_lds((const GLOBAL_AS void*)src,
                                             (LDS_AS void*)dst, 16, 0, 0);
        }
    };

    float ezc0 = e2s[colhalf + l16];
    float ezc1 = e2s[colhalf + 16 + l16];
    stage(0, 0);

    for (int ct = 0; ct < NT; ++ct) {
        const int cur = ct & 1;
        __syncthreads();                  // drains each wave's DMA (vmcnt 0)
        if (ct + 1 < NT) stage(ct + 1, cur ^ 1);
        const int nxt = (ct + 1 < NT) ? ct + 1 : ct;
        float ezn0 = e2s[colhalf + nxt*CTILE + l16];
        float ezn1 = e2s[colhalf + nxt*CTILE + 16 + l16];

        const int colbase = colhalf + ct * CTILE;
        #pragma unroll
        for (int sub = 0; sub < 2; ++sub) {
            const float ez = sub ? ezc1 : ezc0;
            f32x4 acc[4];
            #pragma unroll
            for (int rs = 0; rs < 4; ++rs) acc[rs] = (f32x4){ez, ez, ez, ez};
            #pragma unroll
            for (int cp = 0; cp < 4; ++cp) {
                i64x2 b = *(const i64x2*)&Bb[cur][(sub*4 + cp)*1024 + lane*16];
                #pragma unroll
                for (int rs = 0; rs < 4; ++rs) {
                    acc[rs] = __builtin_amdgcn_mfma_f32_16x16x32_fp8_fp8(A[rs][2*cp],   b.x, acc[rs], 0, 0, 0);
                    acc[rs] = __builtin_amdgcn_mfma_f32_16x16x32_fp8_fp8(A[rs][2*cp+1], b.y, acc[rs], 0, 0, 0);
                }
            }
            const unsigned colv = (unsigned)(colbase + sub*16 + l16);
            // C layout: row = quad*4 + r, col = l16. Pack idx into low 12
            // mantissa bits -> single v_min_f32 keeps (score, idx) together.
            #pragma unroll
            for (int rs = 0; rs < 4; ++rs)
                #pragma unroll
                for (int r = 0; r < 4; ++r) {
                    unsigned pk = (__float_as_uint(acc[rs][r]) & 0xFFFFF000u) | colv;
                    rmin[rs][r] = fminf(rmin[rs][r], __uint_as_float(pk));
                }
        }
        ezc0 = ezn0; ezc1 = ezn1;
    }

    // ---- Reduce across the 16 lanes of each quad, emit packed winner ----
    #pragma unroll
    for (int rs = 0; rs < 4; ++rs) {
        #pragma unroll
        for (int r = 0; r < 4; ++r) {
            float v = rmin[rs][r];
            v = fminf(v, __shfl_xor(v, 8));
            v = fminf(v, __shfl_xor(v, 4));
            v = fminf(v, __shfl_xor(v, 2));
            v = fminf(v, __shfl_xor(v, 1));
            if (l16 == 0)
                cand[(size_t)split * NROWS + waverow + rs*16 + quad*4 + r] = v;
        }
    }
}

// K2: merge splits, gather emb[idx] (fp32 exact), write out, per-block loss partial.
__global__ __launch_bounds__(256) void vq_out(
        const float* __restrict__ x, const float* __restrict__ emb,
        const float* __restrict__ cand, float* __restrict__ out,
        float* __restrict__ partial) {
    __shared__ int idx_lds[64];
    __shared__ float wsum[4];
    const int tid = threadIdx.x;
    const int rowblock = blockIdx.x * 64;
    if (tid < 64) {
        float m = cand[rowblock + tid];
        m = fminf(m, cand[1*NROWS + rowblock + tid]);
        m = fminf(m, cand[2*NROWS + rowblock + tid]);
        m = fminf(m, cand[3*NROWS + rowblock + tid]);
        idx_lds[tid] = (int)(__float_as_uint(m) & 0xFFFu);
    }
    __syncthreads();

    float lsum = 0.f;
    #pragma unroll 4
    for (int it = 0; it < 16; ++it) {
        int fi  = it * 256 + tid;          // 4096 float4 per 64-row tile
        int row = fi >> 6;
        int c4  = fi & 63;
        int e   = idx_lds[row];
        float4 q  = ((const float4*)(emb + (size_t)e * DIM))[c4];
        float4 xv = ((const float4*)(x + (size_t)(rowblock + row) * DIM))[c4];
        ((float4*)(out + (size_t)(rowblock + row) * DIM))[c4] = q;
        float dx = q.x - xv.x, dy = q.y - xv.y, dz = q.z - xv.z, dw = q.w - xv.w;
        lsum += dx*dx + dy*dy + dz*dz + dw*dw;
    }
    #pragma unroll
    for (int off = 32; off; off >>= 1) lsum += __shfl_down(lsum, off);
    int lane = tid & 63, wave = tid >> 6;
    if (lane == 0) wsum[wave] = lsum;
    __syncthreads();
    if (tid == 0) partial[blockIdx.x] = wsum[0] + wsum[1] + wsum[2] + wsum[3];
}

// K3: reduce 1024 partials -> loss (no atomics anywhere).
__global__ void vq_loss(const float* __restrict__ partial, float* __restrict__ loss_slot) {
    __shared__ float wsum[4];
    const int tid = threadIdx.x;
    float s = 0.f;
    #pragma unroll
    for (int i = 0; i < 4; ++i) s += partial[i * 256 + tid];
    #pragma unroll
    for (int off = 32; off; off >>= 1) s += __shfl_down(s, off);
    int lane = tid & 63, wave = tid >> 6;
    if (lane == 0) wsum[wave] = s;
    __syncthreads();
    if (tid == 0)
        loss_slot[0] = (wsum[0] + wsum[1] + wsum[2] + wsum[3]) * (1.25f / 16777216.f);
}

extern "C" void kernel_launch(void* const* d_in, const int* in_sizes, int n_in,
                              void* d_out, int out_size, void* d_ws, size_t ws_size,
                              hipStream_t stream) {
    const float* x   = (const float*)d_in[0];   // [32,2048,256]
    const float* emb = (const float*)d_in[1];   // [4096,256]
    float* out = (float*)d_out;                 // 16777216 quantised_st + 1 loss

    uint8_t* eimg = (uint8_t*)d_ws;                                  // 1 MB
    float* e2s    = (float*)((char*)d_ws + (size_t)VOCAB*DIM);       // 16 KB
    float* cand   = (float*)((char*)e2s + VOCAB*4);                  // 1 MB
    float* partial= (float*)((char*)cand + (size_t)SPLITS*NROWS*4);  // 4 KB
    float* loss_slot = out + (size_t)NROWS * DIM;

    vq_prep<<<VOCAB/16, 256, 0, stream>>>(emb, eimg, e2s);
    vq_argmin<<<(NROWS/RPB)*SPLITS, 128, 0, stream>>>(x, eimg, e2s, cand);
    vq_out<<<NROWS/64, 256, 0, stream>>>(x, emb, cand, out, partial);
    vq_loss<<<1, 256, 0, stream>>>(partial, loss_slot);
}